// Round 8
// baseline (13117.514 us; speedup 1.0000x reference)
//
#include <hip/hip_runtime.h>

// Problem dims
#define Lz   128
#define Hd   1024
#define Od   64
#define Sq   256
#define Bt   512
#define K1   1216   // h1(1024) | z(128) | out(64)  -- fold un-materialized (rank-64)
#define K2q  2048   // h1n(1024) | h2(1024)
#define G4H  4096
#define NBLK 256u   // 8 XCD-teams x 32 blocks; team = batch-slice of 64 rows

typedef __attribute__((ext_vector_type(8))) short  short8;
typedef __attribute__((ext_vector_type(4))) float  floatx4;

__device__ __forceinline__ short f2bf(float x) {
  unsigned u = __float_as_uint(x);
  unsigned r = (u + 0x7fffu + ((u >> 16) & 1u)) >> 16;
  return (short)r;
}
__device__ __forceinline__ float sigf(float x)   { return 1.0f / (1.0f + __expf(-x)); }
__device__ __forceinline__ float tanhf_(float x) { return 1.0f - 2.0f / (__expf(2.0f * x) + 1.0f); }

// weight stream into LDS: sc1 -> bypass the 4MB L2 (no thrash of XCD-local
// activation lines; R6 lesson), MALL-cacheable. Only W uses the LDS-DMA path
// now -- R0..R7 evidence says that path saturates ~0.9 TB/s per XCD.
__device__ __forceinline__ void gl_lds_w(const short* g, void* l) {
  __builtin_amdgcn_global_load_lds(
      (__attribute__((address_space(1))) const void*)g,
      (__attribute__((address_space(3))) void*)l, 16, 0, 16);
}
// h-state store: sc0 (L1 write-through) -> lands in the XCD's shared L2.
__device__ __forceinline__ void st_wt(short* p, short v) {
  asm volatile("global_store_short %0, %1, off sc0"
               :: "v"(p), "v"((unsigned)(unsigned short)v) : "memory");
}

#define S_BARRIER() asm volatile("s_barrier" ::: "memory")
#define WAITVM(n)   asm volatile("s_waitcnt vmcnt(" #n ")" ::: "memory")

// ---- per-XCD barrier over the 32-block team (relaxed agent atomics, proven)
__device__ __forceinline__ void xbar(int* b) {   // b: [cnt, gen]
  __syncthreads();
  if (threadIdx.x == 0) {
    unsigned* cnt = (unsigned*)b;
    unsigned* gen = (unsigned*)b + 1;
    unsigned g = __hip_atomic_load(gen, __ATOMIC_RELAXED, __HIP_MEMORY_SCOPE_AGENT);
    unsigned a = __hip_atomic_fetch_add(cnt, 1u, __ATOMIC_RELAXED, __HIP_MEMORY_SCOPE_AGENT);
    if (a == 31u) {
      __hip_atomic_store(cnt, 0u, __ATOMIC_RELAXED, __HIP_MEMORY_SCOPE_AGENT);
      __hip_atomic_store(gen, g + 1u, __ATOMIC_RELAXED, __HIP_MEMORY_SCOPE_AGENT);
    } else {
      while (__hip_atomic_load(gen, __ATOMIC_RELAXED, __HIP_MEMORY_SCOPE_AGENT) == g)
        __builtin_amdgcn_s_sleep(8);
    }
  }
  __syncthreads();
}

// ---- weight row reorder: group bn (0..63) holds 64 rows: gate g (ifgo), j (0..15)
__device__ __forceinline__ int oldrow(int nr) {
  int bn = nr >> 6, rem = nr & 63, g = rem >> 4, jj = rem & 15;
  return g * Hd + bn * 16 + jj;
}

struct Params {
  const short *W1r, *W2r, *Woutb;
  const float *b0v, *b1v, *bout;
  short *A1_0, *A1_1, *A2_0, *A2_1;
  float *c1, *c2, *out;
  int *barr;   // 8 x 16 ints: per-XCD [cnt, gen, outcnt, teamreg, pad...]
};

// ================= prep kernels =================
__global__ void k_conv_w1a(const float* __restrict__ Whh0, short* __restrict__ W1r) {
  int idx = blockIdx.x * 256 + threadIdx.x;        // 4096*1024
  int nr = idx >> 10, k = idx & 1023;
  W1r[nr * K1 + k] = f2bf(Whh0[oldrow(nr) * Hd + k]);
}
__global__ void k_conv_w1c(const float* __restrict__ Wih0, short* __restrict__ W1r) {
  int idx = blockIdx.x * 256 + threadIdx.x;        // 4096*128 (z cols)
  int nr = idx >> 7, kz = idx & 127;
  W1r[nr * K1 + 1024 + kz] = f2bf(Wih0[oldrow(nr) * (Lz + Od) + kz]);
}
__global__ void k_conv_w1d(const float* __restrict__ Wih0, short* __restrict__ W1r) {
  int idx = blockIdx.x * 256 + threadIdx.x;        // 4096*64 (out-feedback cols)
  int nr = idx >> 6, j = idx & 63;
  W1r[nr * K1 + 1152 + j] = f2bf(Wih0[oldrow(nr) * (Lz + Od) + Lz + j]);
}
__global__ void k_conv_w2(const float* __restrict__ Wih1, const float* __restrict__ Whh1,
                          short* __restrict__ W2r) {
  int idx = blockIdx.x * 256 + threadIdx.x;        // 4096*2048
  int nr = idx >> 11, k = idx & 2047;
  int orow = oldrow(nr);
  float v = (k < Hd) ? Wih1[orow * Hd + k] : Whh1[orow * Hd + (k - Hd)];
  W2r[nr * K2q + k] = f2bf(v);
}
__global__ void k_conv_wout(const float* __restrict__ Wout, short* __restrict__ Woutb) {
  int idx = blockIdx.x * 256 + threadIdx.x;        // 64*1024
  Woutb[idx] = f2bf(Wout[idx]);
}
__global__ void k_vec(const float* __restrict__ bih0, const float* __restrict__ bhh0,
                      const float* __restrict__ bih1, const float* __restrict__ bhh1,
                      float* __restrict__ b0v, float* __restrict__ b1v,
                      int* __restrict__ barzero) {
  int n = blockIdx.x * 256 + threadIdx.x;          // 4096 (original gate order)
  if (n < 256) barzero[n] = 0;                     // zero barrier/team/outcnt state
  b0v[n] = bih0[n] + bhh0[n];
  b1v[n] = bih1[n] + bhh1[n];
}
__global__ void k_init(const float* __restrict__ z, const float* __restrict__ Wh,
                       const float* __restrict__ bh, const float* __restrict__ Wc,
                       const float* __restrict__ bc,
                       short* __restrict__ A1_0, short* __restrict__ A2_0,
                       float* __restrict__ c1, float* __restrict__ c2) {
  int idx = blockIdx.x * 256 + threadIdx.x;        // 512*1024
  int m = idx >> 10, n = idx & 1023;
  const float* zr = z + m * Lz;
  const float* whr = Wh + n * Lz;
  const float* wcr = Wc + n * Lz;
  float hh = bh[n], cc = bc[n];
  #pragma unroll 8
  for (int k = 0; k < Lz; ++k) { float zv = zr[k]; hh += zv * whr[k]; cc += zv * wcr[k]; }
  c1[idx] = cc;
  c2[idx] = cc;
  short hb = f2bf(hh);
  A1_0[m * K1 + n] = hb;                 // h1(-1) = h0
  if (n < Od) A1_0[m * K1 + 1152 + n] = 0;   // out(-1) = 0
  A2_0[m * K2q + Hd + n] = hb;           // h2(-1) = h0
}
__global__ void k_initz(const float* __restrict__ z, short* __restrict__ A1_0,
                        short* __restrict__ A1_1) {
  int idx = blockIdx.x * 256 + threadIdx.x;        // 512*128
  int m = idx >> 7, k = idx & 127;
  short v = f2bf(z[idx]);
  A1_0[m * K1 + 1024 + k] = v;
  A1_1[m * K1 + 1024 + k] = v;
}

// ================= main persistent kernel =================
#define MFMA16(a, b, c) __builtin_amdgcn_mfma_f32_16x16x32_bf16(a, b, c, 0, 0, 0)
#define WBUF  8192    // shorts per W ring buffer: 128 rows x 64 cols
#define NBUF  8       // W ring: depth-4 prefetch, single barrier (NBUF >= depth+2)
#define LDS_BYTES (NBUF * WBUF * 2)   // 128 KB -> exactly 1 block/CU

// A-fragment direct load: 4 x 16B/lane, own-XCD L2 (sc0). Replaces the A half
// of the old LDS staging (256KB/XCD/chunk of redundant LDS-DMA ingest).
#define LDA4(d0, d1, d2, d3, p00, p01, p10, p11, ck) do {                       \
  const int _o = (ck) * 64;                                                     \
  asm volatile("global_load_dwordx4 %0, %1, off sc0" : "=v"(d0) : "v"((p00)+_o) : "memory"); \
  asm volatile("global_load_dwordx4 %0, %1, off sc0" : "=v"(d1) : "v"((p01)+_o) : "memory"); \
  asm volatile("global_load_dwordx4 %0, %1, off sc0" : "=v"(d2) : "v"((p10)+_o) : "memory"); \
  asm volatile("global_load_dwordx4 %0, %1, off sc0" : "=v"(d3) : "v"((p11)+_o) : "memory"); \
} while (0)

// ---- folded out-projection, register-based (R2-proven pipeline): 4 blocks/XCD,
// 16 batch rows each; h2 from own-XCD L2 (sc0); Wout cached. Fully drains.
__device__ __forceinline__ void out_reg(const short* __restrict__ h2src,
    const short* __restrict__ Wo, const float* __restrict__ boutv,
    float* __restrict__ outp, int tt, int mo,
    short* __restrict__ ofb, int tid, int* __restrict__ ocnt)
{
  const int lane = tid & 63, w = tid >> 6;
  const int l15 = lane & 15, q = lane >> 4;
  const short* ap = h2src + (size_t)(mo + l15) * K2q + Hd + q * 8;
  const short* bp = Wo + (size_t)(w * 16 + l15) * Hd + q * 8;
  floatx4 acc = {};
  short8 A0, B0, A1, B1, A2, B2, A3, B3;
#define OLA(r, kk) asm volatile("global_load_dwordx4 %0, %1, off sc0" \
    : "=v"(r) : "v"(ap + (kk) * 32) : "memory")
#define OLB(r, kk) asm volatile("global_load_dwordx4 %0, %1, off" \
    : "=v"(r) : "v"(bp + (kk) * 32) : "memory")
  OLA(A0, 0); OLB(B0, 0); OLA(A1, 1); OLB(B1, 1);     // group 0 (kk 0,1)
  OLA(A2, 2); OLB(B2, 2); OLA(A3, 3); OLB(B3, 3);     // group 1 (kk 2,3)
  #pragma unroll
  for (int g = 0; g < 16; g += 2) {
    WAITVM(4); __builtin_amdgcn_sched_barrier(0);      // group g retired
    acc = MFMA16(A0, B0, acc); acc = MFMA16(A1, B1, acc);
    if (g + 2 < 16) { OLA(A0, 2*(g+2)); OLB(B0, 2*(g+2));
                      OLA(A1, 2*(g+2)+1); OLB(B1, 2*(g+2)+1); }
    if (g + 3 < 16) { WAITVM(4); } else { WAITVM(0); } // group g+1 retired
    __builtin_amdgcn_sched_barrier(0);
    acc = MFMA16(A2, B2, acc); acc = MFMA16(A3, B3, acc);
    if (g + 3 < 16) { OLA(A2, 2*(g+3)); OLB(B2, 2*(g+3));
                      OLA(A3, 2*(g+3)+1); OLB(B3, 2*(g+3)+1); }
  }
#undef OLA
#undef OLB
  #pragma unroll
  for (int r = 0; r < 4; ++r) {
    int m = mo + q * 4 + r;
    int n = w * 16 + l15;
    float v = acc[r] + boutv[n];
    outp[(size_t)m * (Sq * Od) + (size_t)tt * Od + n] = v;
    if (ofb) st_wt(ofb + (size_t)m * K1 + 1152 + n, f2bf(v));
  }
  WAITVM(0);          // each wave drains its own feedback stores
  __syncthreads();    // all waves' stores in L2 before publishing
  if (ocnt && tid == 0)
    __hip_atomic_fetch_add(ocnt, 1, __ATOMIC_RELAXED, __HIP_MEMORY_SCOPE_AGENT);
}

// 64x128 tile, 4 waves: w = mh*2+gh. W-only LDS ring (XOR-swizzled, depth 4,
// NBUF=8, single barrier/chunk). A-frags direct-to-VGPR, double-buffered one
// chunk ahead (sets X=even, Y=odd chunks).
// Per-iteration issue order (fixed, for exact vmcnt counts):
//   A(kk+1) [4 loads] ; W(kk+4) [4 gl_lds]
// Steady state outstanding at wait: W(kk+1),W(kk+2),A(kk),W(kk+3),A(kk+1),W(kk+4)
//   -> WAITVM(12) retires A(kk)+W(kk..kk+2). Tails derived analogously.
__device__ __forceinline__ void gemm_win(
    const short* __restrict__ Asrc, int astride, int nk,
    const short* __restrict__ Wsrc,
    const float* __restrict__ bz, float cr[2][4],
    short* __restrict__ hd0, int hs0, int ho0,
    short* __restrict__ hd1, int hs1, int ho1,
    int m0, int bn2, short* sm, int tid,
    int* __restrict__ ocnt, int othresh)
{
  const int lane = tid & 63, w = tid >> 6;
  const int l15 = lane & 15, q = lane >> 4;
  const int mh = w >> 1, gh = w & 1;
  floatx4 acc[2][4] = {};

  const short* Ab = Asrc + (size_t)m0 * astride;
  const short* Wb = Wsrc + (size_t)(bn2 * 128) * astride;

  // per-lane A base pointers: rows mh*32 + {0,16} + l15, k-offset q*8 (+32 for ks=1)
  const short* a00 = Ab + (size_t)(mh * 32 + l15) * astride + q * 8;
  const short* a01 = a00 + 32;
  const short* a10 = a00 + (size_t)16 * astride;
  const short* a11 = a10 + 32;

  auto stageW = [&](int ck, int b) {
    short* ws = sm + b * WBUF;
    #pragma unroll
    for (int i = 0; i < 4; ++i) {
      int s = i * 256 + tid;
      int row = s >> 3, cg = (s & 7) ^ (row & 7);
      gl_lds_w(Wb + (size_t)row * astride + ck * 64 + cg * 8, ws + s * 8);
    }
  };
  auto guard = [&](int ck) {
    if (ocnt && ck == nk - 1) {
      while (__hip_atomic_load(ocnt, __ATOMIC_RELAXED, __HIP_MEMORY_SCOPE_AGENT) < othresh)
        __builtin_amdgcn_s_sleep(1);
    }
  };
  auto computeC = [&](const short8& f00, const short8& f01,
                      const short8& f10, const short8& f11, const short* ws) {
    #pragma unroll
    for (int ks = 0; ks < 2; ++ks) {
      const int cc = ks * 4 + q;
      const short8 a0 = ks ? f01 : f00;
      const short8 a1 = ks ? f11 : f10;
      #pragma unroll
      for (int g = 0; g < 4; ++g) {
        const int rw = gh * 64 + g * 16 + l15;
        short8 b = *(const short8*)(ws + (rw * 8 + (cc ^ (rw & 7))) * 8);
        acc[0][g] = MFMA16(a0, b, acc[0][g]);
        acc[1][g] = MFMA16(a1, b, acc[1][g]);
      }
    }
  };

  short8 x00, x01, x10, x11, y00, y01, y10, y11;

  // prologue: A(0) then W(0..3)  [outstanding: 4 + 16]
  LDA4(x00, x01, x10, x11, a00, a01, a10, a11, 0);
  stageW(0, 0); stageW(1, 1); stageW(2, 2); stageW(3, 3);

  for (int kk = 0; kk < nk; kk += 2) {
    // ---- even chunk kk (A-frags in X; loads next into Y)
    {
      const int cL = kk + 1;
      if (cL < nk) { guard(cL); LDA4(y00, y01, y10, y11, a00, a01, a10, a11, cL); }
      const int cW = kk + 4;
      if (cW < nk) stageW(cW, cW & 7);
      if (kk == 0)            { WAITVM(20); }   // retire A(0)+W(0) of 28
      else if (kk + 4 < nk)   { WAITVM(12); }
      else if (kk + 3 < nk)   { WAITVM(8);  }
      else if (kk + 1 < nk)   { WAITVM(4);  }
      else                    { WAITVM(0);  }
      __builtin_amdgcn_sched_barrier(0);
      S_BARRIER();
      computeC(x00, x01, x10, x11, sm + (kk & 7) * WBUF);
    }
    // ---- odd chunk kk+1 (A-frags in Y; loads next into X)
    const int k1 = kk + 1;
    if (k1 < nk) {
      const int cL = k1 + 1;
      if (cL < nk) { guard(cL); LDA4(x00, x01, x10, x11, a00, a01, a10, a11, cL); }
      const int cW = k1 + 4;
      if (cW < nk) stageW(cW, cW & 7);
      if (k1 + 4 < nk)        { WAITVM(12); }
      else if (k1 + 3 < nk)   { WAITVM(8);  }
      else if (k1 + 1 < nk)   { WAITVM(4);  }
      else                    { WAITVM(0);  }
      __builtin_amdgcn_sched_barrier(0);
      S_BARRIER();
      computeC(y00, y01, y10, y11, sm + (k1 & 7) * WBUF);
    }
  }

  // fused LSTM cell epilogue; h stored to the XCD-shared L2 (sc0)
  #pragma unroll
  for (int mt = 0; mt < 2; ++mt) {
    #pragma unroll
    for (int r = 0; r < 4; ++r) {
      const int mg = m0 + mh * 32 + mt * 16 + q * 4 + r;
      const int colh = bn2 * 32 + gh * 16 + l15;
      float iv = acc[mt][0][r] + bz[0];
      float fv = acc[mt][1][r] + bz[1];
      float gv = acc[mt][2][r] + bz[2];
      float ov = acc[mt][3][r] + bz[3];
      float cn = sigf(fv) * cr[mt][r] + sigf(iv) * tanhf_(gv);
      cr[mt][r] = cn;
      short hb = f2bf(sigf(ov) * tanhf_(cn));
      st_wt(hd0 + (size_t)mg * hs0 + ho0 + colh, hb);
      if (hd1) st_wt(hd1 + (size_t)mg * hs1 + ho1 + colh, hb);
    }
  }
}

__global__ __launch_bounds__(256, 1) void lstm_main(Params p) {
  extern __shared__ __align__(16) short smem[];   // 8 x 16 KB = 128 KB (W ring)
  const int tid = threadIdx.x;

  // ---- dynamic XCD-team formation (128KB LDS -> 1 block/CU -> 32 blocks/XCD)
  __shared__ int sh_ids[2];
  if (tid == 0) {
    unsigned xr;
    asm volatile("s_getreg_b32 %0, hwreg(HW_REG_XCC_ID)" : "=s"(xr));
    int xcc = (int)(xr & 7u);
    int slot = (int)__hip_atomic_fetch_add((unsigned*)(p.barr + xcc * 16 + 3), 1u,
                                           __ATOMIC_RELAXED, __HIP_MEMORY_SCOPE_AGENT);
    sh_ids[0] = xcc;
    sh_ids[1] = slot & 31;
  }
  __syncthreads();
  const int xcc  = sh_ids[0];
  const int slot = sh_ids[1];
  int* xb = p.barr + xcc * 16;          // [0]=cnt [1]=gen [2]=outcnt

  const int m0 = xcc * 64;              // this XCD's batch slice (64 rows)
  const int bn2 = slot;                 // gate-col slice: h-cols [slot*32, +32)
  const bool ojob = ((slot & 7) == 0);  // 4 out-jobs per XCD
  const int mo = xcc * 64 + (slot >> 3) * 16;   // out-job batch rows (16 each)

  const int lane = tid & 63, w = tid >> 6;
  const int l15 = lane & 15, q = lane >> 4;
  const int mh = w >> 1, gh = w & 1;
  const int colh = bn2 * 32 + gh * 16 + l15;

  float bA[4], bB[4], c1r[2][4], c2r[2][4];
  #pragma unroll
  for (int g = 0; g < 4; ++g) {
    bA[g] = p.b0v[g * Hd + colh];
    bB[g] = p.b1v[g * Hd + colh];
  }
  #pragma unroll
  for (int mt = 0; mt < 2; ++mt)
    #pragma unroll
    for (int r = 0; r < 4; ++r) {
      const int mg = m0 + mh * 32 + mt * 16 + q * 4 + r;
      c1r[mt][r] = p.c1[mg * Hd + colh];
      c2r[mt][r] = p.c2[mg * Hd + colh];
    }

  for (int t = 0; t < Sq; ++t) {
    const int par = t & 1;
    const short* A1p = par ? p.A1_1 : p.A1_0;
    short* A1n = par ? p.A1_0 : p.A1_1;
    short* A2p = par ? p.A2_1 : p.A2_0;
    short* A2n = par ? p.A2_0 : p.A2_1;
    // out(t-1) on designated blocks (reads h2(t-1) from this XCD's L2, writes
    // feedback into A1p out-segment + bumps outcnt). Other blocks proceed into
    // window A and only wait at the out-feedback A-load (chunk 18).
    if (ojob && t > 0)
      out_reg(A2p, p.Woutb, p.bout, p.out, t - 1, mo, (short*)A1p, tid, xb + 2);
    // window A: layer-0 gates; A1 = [h1 | z | out(t-1)], out-chunk flag-guarded
    gemm_win(A1p, K1, 19, p.W1r, bA, c1r,
             A1n, K1, 0, (short*)A2p, K2q, 0, m0, bn2, smem, tid,
             xb + 2, 4 * t);
    xbar(xb);
    // window B: layer-1 gates; h2n only into A2n
    gemm_win(A2p, K2q, 32, p.W2r, bB, c2r,
             A2n, K2q, Hd, (short*)nullptr, 0, 0, m0, bn2, smem, tid,
             nullptr, 0);
    xbar(xb);
  }
  // final: out(255) from h2(255) in A2_0 (phase B of t=255 wrote A2n = A2_0)
  if (ojob)
    out_reg(p.A2_0, p.Woutb, p.bout, p.out, Sq - 1, mo, (short*)nullptr, tid, nullptr);
}

// ================= host =================
extern "C" void kernel_launch(void* const* d_in, const int* in_sizes, int n_in,
                              void* d_out, int out_size, void* d_ws, size_t ws_size,
                              hipStream_t stream) {
  const float* z    = (const float*)d_in[0];
  const float* Wh   = (const float*)d_in[1];
  const float* bh   = (const float*)d_in[2];
  const float* Wc   = (const float*)d_in[3];
  const float* bc   = (const float*)d_in[4];
  const float* Wih0 = (const float*)d_in[5];
  const float* Whh0 = (const float*)d_in[6];
  const float* bih0 = (const float*)d_in[7];
  const float* bhh0 = (const float*)d_in[8];
  const float* Wih1 = (const float*)d_in[9];
  const float* Whh1 = (const float*)d_in[10];
  const float* bih1 = (const float*)d_in[11];
  const float* bhh1 = (const float*)d_in[12];
  const float* Wout = (const float*)d_in[13];
  const float* bout = (const float*)d_in[14];
  float* out = (float*)d_out;

  char* ws = (char*)d_ws;
  size_t off = 0;
  auto carve = [&](size_t bytes) { char* p = ws + off; off = (off + bytes + 255) & ~size_t(255); return p; };
  short* W1r   = (short*)carve((size_t)G4H * K1 * 2);
  short* W2r   = (short*)carve((size_t)G4H * K2q * 2);
  short* Woutb = (short*)carve((size_t)Od * Hd * 2);
  float* b0v   = (float*)carve(G4H * 4);
  float* b1v   = (float*)carve(G4H * 4);
  short* A1_0  = (short*)carve((size_t)Bt * K1 * 2);
  short* A1_1  = (short*)carve((size_t)Bt * K1 * 2);
  short* A2_0  = (short*)carve((size_t)Bt * K2q * 2);
  short* A2_1  = (short*)carve((size_t)Bt * K2q * 2);
  float* c1    = (float*)carve((size_t)Bt * Hd * 4);
  float* c2    = (float*)carve((size_t)Bt * Hd * 4);
  int*   barr  = (int*)carve(1024);  // 8 XCDs x 16 ints: [cnt,gen,outcnt,team,...]

  k_conv_w1a<<<16384, 256, 0, stream>>>(Whh0, W1r);
  k_conv_w1c<<<2048, 256, 0, stream>>>(Wih0, W1r);
  k_conv_w1d<<<1024, 256, 0, stream>>>(Wih0, W1r);
  k_conv_w2 <<<32768, 256, 0, stream>>>(Wih1, Whh1, W2r);
  k_conv_wout<<<256, 256, 0, stream>>>(Wout, Woutb);
  k_vec<<<16, 256, 0, stream>>>(bih0, bhh0, bih1, bhh1, b0v, b1v, barr);
  k_init<<<2048, 256, 0, stream>>>(z, Wh, bh, Wc, bc, A1_0, A2_0, c1, c2);
  k_initz<<<256, 256, 0, stream>>>(z, A1_0, A1_1);

  Params pr{W1r, W2r, Woutb, b0v, b1v, bout,
            A1_0, A1_1, A2_0, A2_1, c1, c2, out, barr};

  (void)hipFuncSetAttribute((const void*)lstm_main,
                            hipFuncAttributeMaxDynamicSharedMemorySize, LDS_BYTES);
  lstm_main<<<dim3(NBLK), dim3(256), LDS_BYTES, stream>>>(pr);
}